// Round 10
// baseline (561.457 us; speedup 1.0000x reference)
//
#include <hip/hip_runtime.h>
#include <hip/hip_bf16.h>
#include <math.h>

#define IN_CH 128
#define HID 64
#define OUT_CH 40

typedef const __hip_bfloat16* bf16p;

// ---- flag detection: flags[0]=1 if float tensors are f32, flags[1]=1 if indices are int64
__global__ void k_detect(const void* x, const void* ei, int* flags) {
    __shared__ int s_f32, s_hi;
    if (threadIdx.x == 0) { s_f32 = 0; s_hi = 0; }
    __syncthreads();
    const __hip_bfloat16* xb = (const __hip_bfloat16*)x;
    const int* ii = (const int*)ei;
    int lf = 0, lh = 0;
    for (int i = threadIdx.x; i < 4096; i += blockDim.x) {
        float f = __bfloat162float(xb[i]);
        if (!(fabsf(f) <= 1e4f)) lf = 1;       // huge/NaN -> buffer is really f32
        lh |= ii[2 * i + 1];                    // int64 high words are all zero
    }
    if (lf) atomicOr(&s_f32, 1);
    if (lh) atomicOr(&s_hi, 1);
    __syncthreads();
    if (threadIdx.x == 0) { flags[0] = s_f32 ? 1 : 0; flags[1] = (s_hi == 0) ? 1 : 0; }
}

// ---- weights to f32: wf = [W1f 8192 | b1f 64 | W2f 2560 | b2f 40], then
//      w1t[8192]: transposed W1, w1t[c*128+k] = W1[k][c]  (for scalar-operand GEMM1)
__global__ void k_convw(const void* W1, const void* b1, const void* W2, const void* b2,
                        const int* flags, float* wf, float* w1t) {
    int i = blockIdx.x * blockDim.x + threadIdx.x;
    if (i >= 19048) return;
    int isF32 = flags[0];
    if (i < 10856) {
        const void* src; int off;
        if (i < 8192)       { src = W1; off = i; }
        else if (i < 8256)  { src = b1; off = i - 8192; }
        else if (i < 10816) { src = W2; off = i - 8256; }
        else                { src = b2; off = i - 10816; }
        float v;
        if (isF32) v = ((const float*)src)[off];
        else       v = __bfloat162float(((bf16p)src)[off]);
        wf[i] = v;
    } else {
        int t = i - 10856;
        int c = t >> 7, k = t & 127;
        float v;
        if (isF32) v = ((const float*)W1)[k * HID + c];
        else       v = __bfloat162float(((bf16p)W1)[k * HID + c]);
        w1t[t] = v;
    }
}

// ---- in-degree histogram over col (int)
__global__ void k_deg(const int* ei, const int* flags, int* deg, int E) {
    int e = blockIdx.x * blockDim.x + threadIdx.x;
    if (e >= E) return;
    int c;
    if (flags[1]) c = ei[2 * (E + e)];
    else          c = ei[E + e];
    atomicAdd(&deg[c], 1);
}

__global__ void k_dinv(const int* deg, float* dinv, int N) {
    int i = blockIdx.x * blockDim.x + threadIdx.x;
    if (i >= N) return;
    dinv[i] = rsqrtf((float)deg[i] + 1.0f);   // +1 = self-loop
}

// ---- exclusive scan over deg -> rowstart (3 kernels)
__global__ void k_blocksum(const int* deg, int* bsum, int N) {
    __shared__ int s[256];
    int i = blockIdx.x * 256 + threadIdx.x;
    s[threadIdx.x] = (i < N) ? deg[i] : 0;
    __syncthreads();
    for (int off = 128; off > 0; off >>= 1) {
        if (threadIdx.x < off) s[threadIdx.x] += s[threadIdx.x + off];
        __syncthreads();
    }
    if (threadIdx.x == 0) bsum[blockIdx.x] = s[0];
}

__global__ void k_scanbsum(int* bsum, int NB) {
    __shared__ int s[1024];
    __shared__ int carry_s;
    if (threadIdx.x == 0) carry_s = 0;
    __syncthreads();
    for (int base = 0; base < NB; base += 1024) {
        int i = base + threadIdx.x;
        int v = (i < NB) ? bsum[i] : 0;
        s[threadIdx.x] = v;
        __syncthreads();
        for (int off = 1; off < 1024; off <<= 1) {
            int t = (threadIdx.x >= off) ? s[threadIdx.x - off] : 0;
            __syncthreads();
            s[threadIdx.x] += t;
            __syncthreads();
        }
        int total = s[1023];
        int excl = s[threadIdx.x] - v + carry_s;
        if (i < NB) bsum[i] = excl;
        __syncthreads();
        if (threadIdx.x == 0) carry_s += total;
        __syncthreads();
    }
}

// rowstart + pre-seeded fill (saves a random load per edge in k_scatter)
__global__ void k_scanfinal(const int* deg, const int* boff, int* rowstart, int* fill, int N) {
    __shared__ int s[256];
    int i = blockIdx.x * 256 + threadIdx.x;
    int v = (i < N) ? deg[i] : 0;
    s[threadIdx.x] = v;
    __syncthreads();
    for (int off = 1; off < 256; off <<= 1) {
        int t = (threadIdx.x >= off) ? s[threadIdx.x - off] : 0;
        __syncthreads();
        s[threadIdx.x] += t;
        __syncthreads();
    }
    if (i < N) {
        int rs = boff[blockIdx.x] + s[threadIdx.x] - v;
        rowstart[i] = rs;
        fill[i] = rs;
    }
    if (i == N - 1) rowstart[N] = boff[blockIdx.x] + s[threadIdx.x];
}

// ---- bucket-scatter edges into CSR, XCD-sliced; r loaded ONLY for passing edges
__global__ void k_scatter(const int* ei, const int* flags, int* fill, int* erow,
                          int E, int N) {
    int slice = blockIdx.x & 7;
    int nlo = (int)(((long)N * slice) >> 3);
    int nhi = (int)(((long)N * (slice + 1)) >> 3);
    int nblk = gridDim.x >> 3;
    int bid = blockIdx.x >> 3;
    int i64 = flags[1];
    for (int e = bid * 256 + threadIdx.x; e < E; e += nblk * 256) {
        int c;
        if (i64) c = ei[2 * (E + e)];
        else     c = ei[E + e];
        if (c >= nlo && c < nhi) {
            int r;
            if (i64) r = ei[2 * e];
            else     r = ei[e];
            int pos = atomicAdd(&fill[c], 1);
            erow[pos] = r;
        }
    }
}

// ---- GEMM1, lane=node / scalar-W1 structure (no LDS, no broadcast loads):
//      each lane owns a node; W1 read via wave-uniform s_load from w1t[c][k];
//      x unpacked bf16->f32 with bit ops. acc[64] in VGPRs.
__global__ __launch_bounds__(256) void k_gemm1(const void* x, const float* w1t,
                                               __hip_bfloat16* h1b, const int* flags, int N) {
    const int lane = threadIdx.x & 63;
    const int wid = blockIdx.x * 4 + (threadIdx.x >> 6);
    const int nwaves = gridDim.x * 4;
    const int isF32 = flags[0];
    for (int base = wid * 64; base < N; base += nwaves * 64) {
        int node = base + lane;
        int nc = node < N ? node : N - 1;
        float acc[HID];
        #pragma unroll
        for (int c = 0; c < HID; ++c) acc[c] = 0.f;
        if (!isF32) {
            const unsigned* xr = (const unsigned*)x + (size_t)nc * (IN_CH / 2);
            #pragma unroll 1
            for (int ch = 0; ch < 8; ++ch) {          // k-chunks of 16
                unsigned raw[8];
                #pragma unroll
                for (int j = 0; j < 8; ++j) raw[j] = xr[ch * 8 + j];
                float xf[16];
                #pragma unroll
                for (int j = 0; j < 8; ++j) {
                    xf[2*j]   = __uint_as_float(raw[j] << 16);
                    xf[2*j+1] = __uint_as_float(raw[j] & 0xffff0000u);
                }
                #pragma unroll
                for (int c = 0; c < HID; ++c) {
                    const float* wv = w1t + c * IN_CH + ch * 16;   // wave-uniform -> s_load
                    #pragma unroll
                    for (int kk = 0; kk < 16; ++kk)
                        acc[c] += xf[kk] * wv[kk];
                }
            }
        } else {
            const float* xr = (const float*)x + (size_t)nc * IN_CH;
            #pragma unroll 1
            for (int ch = 0; ch < 8; ++ch) {
                float xf[16];
                #pragma unroll
                for (int j = 0; j < 16; ++j) xf[j] = xr[ch * 16 + j];
                #pragma unroll
                for (int c = 0; c < HID; ++c) {
                    const float* wv = w1t + c * IN_CH + ch * 16;
                    #pragma unroll
                    for (int kk = 0; kk < 16; ++kk)
                        acc[c] += xf[kk] * wv[kk];
                }
            }
        }
        if (node < N) {
            unsigned* dst = (unsigned*)(h1b + (size_t)node * HID);
            #pragma unroll
            for (int j = 0; j < 32; ++j) {
                __hip_bfloat16 lo = __float2bfloat16(acc[2*j]);
                __hip_bfloat16 hi = __float2bfloat16(acc[2*j+1]);
                unsigned u = ((unsigned)*(unsigned short*)&hi << 16) | *(unsigned short*)&lo;
                dst[j] = u;
            }
        }
    }
}

// ---- Fused aggregation1 (+self-loop+bias+ReLU) AND GEMM2: one wave per node.
//      Gather bf16 h1 (128 B/edge), g via LDS round-trip, h2 stored as bf16 40ch.
__global__ __launch_bounds__(256) void k_agg1gemm2(const int* rowstart, const int* erow,
        const __hip_bfloat16* h1b, const float* dinv, const float* b1f, const float* w2f,
        __hip_bfloat16* h2b, int N) {
    __shared__ float w2[HID * OUT_CH];   // 2560 floats
    __shared__ float sg[256];            // per-wave g slices
    for (int i = threadIdx.x; i < HID * OUT_CH; i += 256) w2[i] = w2f[i];
    __syncthreads();

    int w = (blockIdx.x * 256 + threadIdx.x) >> 6;
    int c = threadIdx.x & 63;
    bool act = (w < N);
    float g = 0.f;
    if (act) {
        int s0 = __builtin_amdgcn_readfirstlane(rowstart[w]);
        int s1 = __builtin_amdgcn_readfirstlane(rowstart[w + 1]);
        float d = dinv[w];
        float acc = __bfloat162float(h1b[(size_t)w * HID + c]) * d * d + b1f[c];
        int i = s0;
        for (; i + 1 < s1; i += 2) {
            int r0 = erow[i];     int r1 = erow[i + 1];
            float n0 = dinv[r0] * d;
            float n1 = dinv[r1] * d;
            float v0 = __bfloat162float(h1b[(size_t)r0 * HID + c]);
            float v1 = __bfloat162float(h1b[(size_t)r1 * HID + c]);
            acc += v0 * n0 + v1 * n1;
        }
        if (i < s1) {
            int r = erow[i];
            acc += __bfloat162float(h1b[(size_t)r * HID + c]) * (dinv[r] * d);
        }
        g = fmaxf(acc, 0.f);
    }
    sg[threadIdx.x] = g;
    __syncthreads();
    if (act && c < OUT_CH) {
        const float* gs = sg + (threadIdx.x & 192);   // this wave's 64-slice
        float acc2 = 0.f;
        #pragma unroll
        for (int k = 0; k < HID; ++k) acc2 += gs[k] * w2[k * OUT_CH + c];
        h2b[(size_t)w * OUT_CH + c] = __float2bfloat16(acc2);
    }
}

// ---- Aggregation 2 (CSR) on bf16 h2 (40ch, 80 B/edge gathers); +b2 -> f32 d_out
__global__ __launch_bounds__(256) void k_agg2(const int* rowstart, const int* erow,
        const __hip_bfloat16* h2b, const float* dinv, const float* b2f,
        float* out, int N) {
    int w = (blockIdx.x * 256 + threadIdx.x) >> 6;
    int c = threadIdx.x & 63;
    if (w >= N) return;
    int s0 = __builtin_amdgcn_readfirstlane(rowstart[w]);
    int s1 = __builtin_amdgcn_readfirstlane(rowstart[w + 1]);
    float d = dinv[w];
    float acc = 0.f;
    if (c < OUT_CH) acc = __bfloat162float(h2b[(size_t)w * OUT_CH + c]) * d * d + b2f[c];
    int i = s0;
    for (; i + 1 < s1; i += 2) {
        int r0 = erow[i];     int r1 = erow[i + 1];
        float n0 = dinv[r0] * d;
        float n1 = dinv[r1] * d;
        if (c < OUT_CH) {
            float v0 = __bfloat162float(h2b[(size_t)r0 * OUT_CH + c]);
            float v1 = __bfloat162float(h2b[(size_t)r1 * OUT_CH + c]);
            acc += v0 * n0 + v1 * n1;
        }
    }
    if (i < s1 && c < OUT_CH) {
        int r = erow[i];
        acc += __bfloat162float(h2b[(size_t)r * OUT_CH + c]) * (dinv[r] * d);
    }
    if (c < OUT_CH) out[(size_t)w * OUT_CH + c] = acc;
}

extern "C" void kernel_launch(void* const* d_in, const int* in_sizes, int n_in,
                              void* d_out, int out_size, void* d_ws, size_t ws_size,
                              hipStream_t stream) {
    const void* x  = d_in[0];
    const void* ei = d_in[1];
    const void* W1 = d_in[2];
    const void* b1 = d_in[3];
    const void* W2 = d_in[4];
    const void* b2 = d_in[5];
    const int N = in_sizes[0] / IN_CH;   // 100000
    const int E = in_sizes[1] / 2;       // 1600000
    const int* eii = (const int*)ei;
    const int NB = (N + 255) / 256;

    // ---- workspace layout (4-byte units). Peak ~29 MiB.
    float* ws = (float*)d_ws;
    size_t off = 16;
    int*   flags    = (int*)ws;
    int*   deg      = (int*)ws + off;            off += N;
    int*   fill     = (int*)ws + off;            off += N;
    float* dinv     = ws + off;                  off += N;
    float* wf       = ws + off;                  off += 10880;
    float* w1t      = ws + off;                  off += 8192;
    int*   bsum     = (int*)ws + off;            off += NB + 16;
    int*   rowstart = (int*)ws + off;            off += N + 1;
    off = (off + 255) & ~(size_t)255;
    int*   erow     = (int*)ws + off;            off += E;
    __hip_bfloat16* h1b = (__hip_bfloat16*)(ws + off);     off += (size_t)N * HID / 2;
    __hip_bfloat16* h2b = (__hip_bfloat16*)(ws + off);     off += (size_t)N * OUT_CH / 2;

    hipMemsetAsync(deg, 0, (size_t)N * sizeof(int), stream);  // deg only; fill pre-seeded

    k_detect<<<1, 256, 0, stream>>>(x, ei, flags);
    k_convw<<<(19048 + 255) / 256, 256, 0, stream>>>(W1, b1, W2, b2, flags, wf, w1t);
    k_deg<<<(E + 255) / 256, 256, 0, stream>>>(eii, flags, deg, E);
    k_dinv<<<(N + 255) / 256, 256, 0, stream>>>(deg, dinv, N);

    k_blocksum<<<NB, 256, 0, stream>>>(deg, bsum, N);
    k_scanbsum<<<1, 1024, 0, stream>>>(bsum, NB);
    k_scanfinal<<<NB, 256, 0, stream>>>(deg, bsum, rowstart, fill, N);
    k_scatter<<<4096, 256, 0, stream>>>(eii, flags, fill, erow, E, N);

    // lane=node gemm1: 1563 waves -> 391 blocks
    int g1blocks = ((N + 63) / 64 + 3) / 4;
    k_gemm1<<<g1blocks, 256, 0, stream>>>(x, w1t, h1b, flags, N);

    int nodeBlocks = (N * 64 + 255) / 256;   // 25000
    k_agg1gemm2<<<nodeBlocks, 256, 0, stream>>>(rowstart, erow, h1b, dinv,
                                                wf + 8192, wf + 8256, h2b, N);
    k_agg2<<<nodeBlocks, 256, 0, stream>>>(rowstart, erow, h2b, dinv,
                                           wf + 10816, (float*)d_out, N);
}